// Round 10
// baseline (849.803 us; speedup 1.0000x reference)
//
#include <hip/hip_runtime.h>
#include <cstdint>
#include <cstddef>

#define E_ 8
#define D_ 1024
#define F_ 4096
#define T_ 16384
#define C_ 2048   // tokens per expert

typedef __attribute__((ext_vector_type(8))) short short8;
typedef __attribute__((ext_vector_type(4))) float f32x4;

// fp32 -> bf16 round-to-nearest-even
__device__ __forceinline__ unsigned short f2b(float f) {
  union { float f; uint32_t u; } v; v.f = f;
  uint32_t u = v.u;
  return (unsigned short)((u + 0x7FFFu + ((u >> 16) & 1u)) >> 16);
}

// tanh-approx gelu (jax.nn.gelu default approximate=True)
__device__ __forceinline__ float gelu_t(float x) {
  float u = 0.7978845608028654f * (x + 0.044715f * x * x * x);
  float e = __expf(2.0f * u);
  return 0.5f * x * (2.0f - 2.0f / (e + 1.0f));  // 0.5x(1+tanh(u))
}

__device__ __forceinline__ void gload_lds16(const void* g, void* l) {
  __builtin_amdgcn_global_load_lds(
      (__attribute__((address_space(1))) void*)g,
      (__attribute__((address_space(3))) void*)l, 16, 0, 0);
}

// ---------------- pre-pass: fp32 -> bf16 elementwise ----------------
__global__ void cvt_bf16_kernel(const float* __restrict__ in,
                                unsigned short* __restrict__ out, int n) {
  int idx = blockIdx.x * blockDim.x + threadIdx.x;
  int stride = gridDim.x * blockDim.x;
  for (int i = idx * 8; i < n; i += stride * 8) {
    float4 a = *(const float4*)(in + i);
    float4 b = *(const float4*)(in + i + 4);
    union { unsigned short s[8]; int4 v; } r;
    r.s[0] = f2b(a.x); r.s[1] = f2b(a.y); r.s[2] = f2b(a.z); r.s[3] = f2b(a.w);
    r.s[4] = f2b(b.x); r.s[5] = f2b(b.y); r.s[6] = f2b(b.z); r.s[7] = f2b(b.w);
    *(int4*)(out + i) = r.v;
  }
}

// ---------------- pre-pass: per-expert transpose + convert ----------------
// in: [E][R][Cc] fp32  ->  out: [E][Cc][R] bf16
__global__ void transpose_cvt(const float* __restrict__ in,
                              unsigned short* __restrict__ out, int R, int Cc) {
  __shared__ float tile_s[32][33];
  const int e = blockIdx.y;
  const int ctiles = Cc >> 5;
  const int rt = blockIdx.x / ctiles, ct = blockIdx.x % ctiles;
  const int r0 = rt * 32, c0 = ct * 32;
  const float* ine = in + (size_t)e * R * Cc;
  unsigned short* oute = out + (size_t)e * R * Cc;
  const int tx = threadIdx.x & 31, ty = threadIdx.x >> 5;  // ty in 0..7
#pragma unroll
  for (int q = 0; q < 4; ++q)
    tile_s[ty + q * 8][tx] = ine[(size_t)(r0 + ty + q * 8) * Cc + c0 + tx];
  __syncthreads();
#pragma unroll
  for (int q = 0; q < 4; ++q) {
    float v = tile_s[tx][ty + q * 8];
    oute[(size_t)(c0 + ty + q * 8) * R + r0 + tx] = f2b(v);
  }
}

// ==== 256x256 bf16 GEMM — 8-phase with CROSS-PHASE READ PIPELINING =======
// r5's proven staging/vmcnt schedule + double fragment sets: phase p issues
// the 12 ds_reads for phase p+1, waits lgkmcnt(12) (retires only the
// consume set), MFMAs on fragments read LAST phase. LDS read service of
// p+1 overlaps the matrix pipe of p. vmcnt moved BEFORE reads at P4/P8.
// A: [E][Mt][Kt] bf16 row-major; B: [E][Nt][Kt] bf16 (row = output column).
// 512 thr = 8 waves (2Mx4N per 128x128 quadrant). K-tile=64, LDS half-tiles
// [128][64] bf16, slots A0,A1,B0,B1 per parity; +16 KiB pad (144 KiB).
// Per-row 8-chunk XOR swizzle (slot^(row&7)), both-sides (rule #21).
template <int Mt, int Nt, int Kt, int EPI>
__global__ __launch_bounds__(512, 2)
void gemmP(const unsigned short* __restrict__ A,
           const unsigned short* __restrict__ B,
           const float* __restrict__ bias, void* __restrict__ Cout) {
  constexpr int NT = Kt / 64;       // K-tiles
  constexpr int NI = NT / 2;        // iterations
  constexpr int MB = Mt / 256, NB = Nt / 256;
  static_assert(NT >= 4 && (NT % 2) == 0, "");

  // bijective XCD swizzle (nwg % 8 == 0 for all our grids)
  const int nwg = E_ * MB * NB;
  const int bid = blockIdx.x;
  const int swzb = (bid & 7) * (nwg >> 3) + (bid >> 3);
  const int e = swzb / (MB * NB);
  const int rem = swzb % (MB * NB);
  const int mblk = rem / NB, nblk = rem % NB;

  const unsigned short* Ae = A + ((size_t)e * Mt + mblk * 256) * Kt;
  const unsigned short* Be = B + ((size_t)e * Nt + nblk * 256) * Kt;

  __shared__ unsigned short lds[73728];  // 144 KiB (8 half-slots + pad)

  const int tid = threadIdx.x;
  const int lane = tid & 63, wave = tid >> 6;
  const int wm = wave >> 2, wn = wave & 3;  // 2 x 4 within each quadrant
  const int ls = lane >> 4, lr = lane & 15;

  // staging: chunk c in [0,1024) of a half-tile: row=c>>3, slot=c&7,
  // global chunk g = (c&7)^(row&7); LDS dest linear c*16B (both-sides swz).
  const int c0 = tid, c1 = tid + 512;
  const int r0c = c0 >> 3, g0c = (c0 & 7) ^ (r0c & 7);
  const int r1c = c1 >> 3, g1c = (c1 & 7) ^ (r1c & 7);

  auto stA = [&](int rh, int p, int t, bool valid) {
    unsigned short* dst = valid ? (lds + (size_t)(p * 4 + rh) * 8192)
                                : (lds + 65536);
    const int tt = valid ? t : NT - 1;
    const unsigned short* s = Ae + (size_t)rh * 128 * Kt + tt * 64;
    gload_lds16(s + (size_t)r0c * Kt + g0c * 8, dst + c0 * 8);
    gload_lds16(s + (size_t)r1c * Kt + g1c * 8, dst + c1 * 8);
  };
  auto stB = [&](int ch, int p, int t, bool valid) {
    unsigned short* dst = valid ? (lds + (size_t)(p * 4 + 2 + ch) * 8192)
                                : (lds + 65536);
    const int tt = valid ? t : NT - 1;
    const unsigned short* s = Be + (size_t)ch * 128 * Kt + tt * 64;
    gload_lds16(s + (size_t)r0c * Kt + g0c * 8, dst + c0 * 8);
    gload_lds16(s + (size_t)r1c * Kt + g1c * 8, dst + c1 * 8);
  };

  f32x4 acc[2][2][4][2] = {};  // [rh][ch][m][n]

  // bias fragments first (oldest vmem, drained by prologue vmcnt)
  const float* be = bias + (size_t)e * Nt + nblk * 256;
  float bvf[2][2];
#pragma unroll
  for (int ch = 0; ch < 2; ++ch)
#pragma unroll
    for (int n = 0; n < 2; ++n)
      bvf[ch][n] = be[ch * 128 + wn * 32 + n * 16 + lr];

  // prologue staging: tile0 full + A0s1,B1s1 of tile1 (r5 order)
  stA(0, 0, 0, true); stB(1, 0, 0, true); stA(1, 0, 0, true);
  stB(0, 0, 0, true); stA(0, 1, 1, true); stB(1, 1, 1, true);
  asm volatile("s_waitcnt vmcnt(4)" ::: "memory");  // tile0 halves landed
  __builtin_amdgcn_s_barrier();

  // two fragment register sets (X / Y), statically named (rule #20)
  short8 faX[4][2], fbX[2][2], faY[4][2], fbY[2][2];

// read 12 frags of tuple (SLOT,RH,CH) into set (FA,FB)
#define RD12(FA, FB, SLOT, RH, CH)                                             \
  {                                                                            \
    const unsigned short* sA = lds + (size_t)((SLOT) * 4 + (RH)) * 8192;       \
    const unsigned short* sB = lds + (size_t)((SLOT) * 4 + 2 + (CH)) * 8192;   \
    _Pragma("unroll") for (int m = 0; m < 4; ++m)                              \
      _Pragma("unroll") for (int kk = 0; kk < 2; ++kk) {                       \
        int row = wm * 64 + m * 16 + lr;                                       \
        FA[m][kk] = *(const short8*)(sA + row * 64 +                           \
                                     (((kk << 2) | ls) ^ (row & 7)) * 8);      \
      }                                                                        \
    _Pragma("unroll") for (int n = 0; n < 2; ++n)                              \
      _Pragma("unroll") for (int kk = 0; kk < 2; ++kk) {                       \
        int row = wn * 32 + n * 16 + lr;                                       \
        FB[n][kk] = *(const short8*)(sB + row * 64 +                           \
                                     (((kk << 2) | ls) ^ (row & 7)) * 8);      \
      }                                                                        \
  }

// barrier; retire ONLY the consume set (12 newer stay in flight); MFMA
#define MM16(FA, FB, RH, CH)                                                   \
  __builtin_amdgcn_s_barrier();                                                \
  asm volatile("s_waitcnt lgkmcnt(12)" ::: "memory");                          \
  __builtin_amdgcn_sched_barrier(0);                                           \
  __builtin_amdgcn_s_setprio(1);                                               \
  _Pragma("unroll") for (int m = 0; m < 4; ++m)                                \
    _Pragma("unroll") for (int n = 0; n < 2; ++n)                              \
      _Pragma("unroll") for (int kk = 0; kk < 2; ++kk)                         \
        acc[RH][CH][m][n] = __builtin_amdgcn_mfma_f32_16x16x32_bf16(           \
            FA[m][kk], FB[n][kk], acc[RH][CH][m][n], 0, 0, 0);                 \
  __builtin_amdgcn_s_setprio(0);                                               \
  __builtin_amdgcn_s_barrier();

#define VM2() asm volatile("s_waitcnt vmcnt(2)" ::: "memory")

  // prologue read: P1 tuple (0,0,0) into X
  RD12(faX, fbX, 0, 0, 0)

  for (int i = 0; i < NI; ++i) {
    const int t1 = 2 * i + 1, t2 = 2 * i + 2, t3 = 2 * i + 3;
    const bool v2 = t2 < NT, v3 = t3 < NT;

    // P1: consume X=(0,0,0); read Y <- P2 (0,0,1)
    RD12(faY, fbY, 0, 0, 1) stA(1, 1, t1, true);
    MM16(faX, fbX, 0, 0)
    // P2: consume Y; read X <- P3 (0,1,1)
    RD12(faX, fbX, 0, 1, 1) stB(0, 1, t1, true);
    MM16(faY, fbY, 0, 1)
    // P3: consume X; read Y <- P4 (0,1,0)
    RD12(faY, fbY, 0, 1, 0) stA(0, 0, t2, v2);
    MM16(faX, fbX, 1, 1)
    // P4: vmcnt first (retires P7p,P8p,P1,P2 — covers s1 lookahead reads)
    VM2();
    RD12(faX, fbX, 1, 0, 0) stB(1, 0, t2, v2);
    MM16(faY, fbY, 1, 0)
    // P5: consume X=(1,0,0); read Y <- P6 (1,0,1)
    RD12(faY, fbY, 1, 0, 1) stA(1, 0, t2, v2);
    MM16(faX, fbX, 0, 0)
    // P6: consume Y; read X <- P7 (1,1,1)
    RD12(faX, fbX, 1, 1, 1) stB(0, 0, t2, v2);
    MM16(faY, fbY, 0, 1)
    // P7: consume X; read Y <- P8 (1,1,0)
    RD12(faY, fbY, 1, 1, 0) stA(0, 1, t3, v3);
    MM16(faX, fbX, 1, 1)
    // P8: vmcnt first (retires P3..P6 — covers next-iter s0 lookahead reads)
    VM2();
    RD12(faX, fbX, 0, 0, 0) stB(1, 1, t3, v3);
    MM16(faY, fbY, 1, 0)
    // (final iteration's P8 lookahead frags are simply discarded)
  }
#undef RD12
#undef MM16
#undef VM2

  // drain all staging + reads before LDS reuse / exit
  asm volatile("s_waitcnt vmcnt(0) lgkmcnt(0)" ::: "memory");
  __builtin_amdgcn_s_barrier();

  if constexpr (EPI == 1) {
    // bounce: lds as [256][256] ushort, 16B-chunk XOR swizzle (ch ^= row&7)
#pragma unroll
    for (int rh = 0; rh < 2; ++rh)
#pragma unroll
      for (int ch = 0; ch < 2; ++ch)
#pragma unroll
        for (int m = 0; m < 4; ++m)
#pragma unroll
          for (int n = 0; n < 2; ++n)
#pragma unroll
            for (int i = 0; i < 4; ++i) {
              int row = rh * 128 + wm * 64 + m * 16 + ls * 4 + i;
              int col = ch * 128 + wn * 32 + n * 16 + lr;
              lds[row * 256 + (((col >> 3) ^ (row & 7)) << 3) + (col & 7)] =
                  f2b(gelu_t(acc[rh][ch][m][n][i] + bvf[ch][n]));
            }
    __builtin_amdgcn_s_barrier();
    unsigned short* H = (unsigned short*)Cout;
#pragma unroll
    for (int j = 0; j < 16; ++j) {
      int row = j * 16 + wave * 2 + (lane >> 5);
      int chk = lane & 31;
      int sc = chk ^ (row & 7);
      unsigned short* dst =
          H + ((size_t)e * Mt + mblk * 256 + row) * Nt + nblk * 256 + chk * 8;
      *(int4*)dst = *(const int4*)(lds + row * 256 + sc * 8);
    }
  } else {
    float* O = (float*)Cout;
#pragma unroll
    for (int rh = 0; rh < 2; ++rh)
#pragma unroll
      for (int ch = 0; ch < 2; ++ch)
#pragma unroll
        for (int m = 0; m < 4; ++m)
#pragma unroll
          for (int n = 0; n < 2; ++n)
#pragma unroll
            for (int i = 0; i < 4; ++i) {
              int row = rh * 128 + wm * 64 + m * 16 + ls * 4 + i;
              int col = ch * 128 + wn * 32 + n * 16 + lr;
              O[((size_t)e * Mt + mblk * 256 + row) * Nt + nblk * 256 + col] =
                  acc[rh][ch][m][n][i] + bvf[ch][n];
            }
  }
}

extern "C" void kernel_launch(void* const* d_in, const int* in_sizes, int n_in,
                              void* d_out, int out_size, void* d_ws, size_t ws_size,
                              hipStream_t stream) {
  const float* x = (const float*)d_in[0];
  const float* w1 = (const float*)d_in[1];
  const float* b1 = (const float*)d_in[2];
  const float* w2 = (const float*)d_in[3];
  const float* b2 = (const float*)d_in[4];
  float* out = (float*)d_out;

  unsigned short* ws = (unsigned short*)d_ws;
  unsigned short* xb = ws;                               // [T][D] bf16
  unsigned short* w1t = xb + (size_t)T_ * D_;            // [E][F][D] bf16
  unsigned short* w2t = w1t + (size_t)E_ * F_ * D_;      // [E][D][F] bf16
  unsigned short* h = w2t + (size_t)E_ * D_ * F_;        // [T][F] bf16

  cvt_bf16_kernel<<<2048, 256, 0, stream>>>(x, xb, T_ * D_);
  transpose_cvt<<<dim3((D_ / 32) * (F_ / 32), E_), 256, 0, stream>>>(w1, w1t, D_, F_);
  transpose_cvt<<<dim3((F_ / 32) * (D_ / 32), E_), 256, 0, stream>>>(w2, w2t, F_, D_);

  gemmP<C_, F_, D_, 1>
      <<<E_ * (C_ / 256) * (F_ / 256), 512, 0, stream>>>(xb, w1t, b1, h);
  gemmP<C_, D_, F_, 2>
      <<<E_ * (C_ / 256) * (D_ / 256), 512, 0, stream>>>(h, w2t, b2, out);
}

// Round 11
// 430.906 us; speedup vs baseline: 1.9721x; 1.9721x over previous
//
#include <hip/hip_runtime.h>
#include <cstdint>
#include <cstddef>

#define E_ 8
#define D_ 1024
#define F_ 4096
#define T_ 16384
#define C_ 2048   // tokens per expert

typedef __attribute__((ext_vector_type(8))) short short8;
typedef __attribute__((ext_vector_type(4))) float f32x4;
typedef __attribute__((ext_vector_type(16))) float f32x16;

// fp32 -> bf16 round-to-nearest-even
__device__ __forceinline__ unsigned short f2b(float f) {
  union { float f; uint32_t u; } v; v.f = f;
  uint32_t u = v.u;
  return (unsigned short)((u + 0x7FFFu + ((u >> 16) & 1u)) >> 16);
}

// tanh-approx gelu (jax.nn.gelu default approximate=True)
__device__ __forceinline__ float gelu_t(float x) {
  float u = 0.7978845608028654f * (x + 0.044715f * x * x * x);
  float e = __expf(2.0f * u);
  return 0.5f * x * (2.0f - 2.0f / (e + 1.0f));  // 0.5x(1+tanh(u))
}

__device__ __forceinline__ void gload_lds16(const void* g, void* l) {
  __builtin_amdgcn_global_load_lds(
      (__attribute__((address_space(1))) void*)g,
      (__attribute__((address_space(3))) void*)l, 16, 0, 0);
}

// ---------------- pre-pass: fp32 -> bf16 elementwise ----------------
__global__ void cvt_bf16_kernel(const float* __restrict__ in,
                                unsigned short* __restrict__ out, int n) {
  int idx = blockIdx.x * blockDim.x + threadIdx.x;
  int stride = gridDim.x * blockDim.x;
  for (int i = idx * 8; i < n; i += stride * 8) {
    float4 a = *(const float4*)(in + i);
    float4 b = *(const float4*)(in + i + 4);
    union { unsigned short s[8]; int4 v; } r;
    r.s[0] = f2b(a.x); r.s[1] = f2b(a.y); r.s[2] = f2b(a.z); r.s[3] = f2b(a.w);
    r.s[4] = f2b(b.x); r.s[5] = f2b(b.y); r.s[6] = f2b(b.z); r.s[7] = f2b(b.w);
    *(int4*)(out + i) = r.v;
  }
}

// ---------------- pre-pass: per-expert transpose + convert ----------------
// in: [E][R][Cc] fp32  ->  out: [E][Cc][R] bf16
__global__ void transpose_cvt(const float* __restrict__ in,
                              unsigned short* __restrict__ out, int R, int Cc) {
  __shared__ float tile_s[32][33];
  const int e = blockIdx.y;
  const int ctiles = Cc >> 5;
  const int rt = blockIdx.x / ctiles, ct = blockIdx.x % ctiles;
  const int r0 = rt * 32, c0 = ct * 32;
  const float* ine = in + (size_t)e * R * Cc;
  unsigned short* oute = out + (size_t)e * R * Cc;
  const int tx = threadIdx.x & 31, ty = threadIdx.x >> 5;  // ty in 0..7
#pragma unroll
  for (int q = 0; q < 4; ++q)
    tile_s[ty + q * 8][tx] = ine[(size_t)(r0 + ty + q * 8) * Cc + c0 + tx];
  __syncthreads();
#pragma unroll
  for (int q = 0; q < 4; ++q) {
    float v = tile_s[tx][ty + q * 8];
    oute[(size_t)(c0 + ty + q * 8) * R + r0 + tx] = f2b(v);
  }
}

// ==== 256x256 batched bf16 GEMM — 32x32x16 MFMA core, BK=64, dbuf ========
// A: [E][Mt][Kt] bf16 row-major; B: [E][Nt][Kt] bf16 (row = output column).
// 512 thr = 8 waves (2M x 4N); per-wave 128x64 = 4x2 tiles of 32x32.
// acc: 8 x f32x16 (unified-file AGPR). MFMA: v_mfma_f32_32x32x16_bf16,
// 32/wave/K-tile(64), kh-outermost (dependency distance 8).
// LDS: 2 buffers x (A[256][64] + B[256][64]) bf16 = 128 KiB.
// Per-row 8-slot XOR swizzle: LDS[row][slot] holds global chunk slot^(row&7)
// (both-sides, rule #21; r5's proven-0-conflict layout).
// A-frag(rt,kh): lane reads row wm*128+rt*32+(l&31), chunk 2kh+(l>>5) -> each
// 8-lane beat = 8 distinct slots -> conflict-free. B symmetric.
// Sync: m97/m103 structure — per K-tile {vmcnt(0); barrier; stage(t+1);
// reads+MFMA} (912 TF pedigree at dense 4096^3).
template <int Mt, int Nt, int Kt, int EPI>
__global__ __launch_bounds__(512, 2)
void gemm32(const unsigned short* __restrict__ A,
            const unsigned short* __restrict__ B,
            const float* __restrict__ bias, void* __restrict__ Cout) {
  constexpr int NT = Kt / 64;
  constexpr int MB = Mt / 256, NB = Nt / 256;
  static_assert(NT >= 2, "");

  // bijective XCD swizzle (nwg % 8 == 0 for all our grids)
  const int nwg = E_ * MB * NB;
  const int bid = blockIdx.x;
  const int swzb = (bid & 7) * (nwg >> 3) + (bid >> 3);
  const int e = swzb / (MB * NB);
  const int rem = swzb % (MB * NB);
  const int mblk = rem / NB, nblk = rem % NB;

  const unsigned short* Ae = A + ((size_t)e * Mt + mblk * 256) * Kt;
  const unsigned short* Be = B + ((size_t)e * Nt + nblk * 256) * Kt;

  __shared__ unsigned short lds[65536];  // 128 KiB

  const int tid = threadIdx.x;
  const int lane = tid & 63, wave = tid >> 6;
  const int wm = wave >> 2, wn = wave & 3;  // 2M x 4N
  const int l31 = lane & 31, l5 = lane >> 5;

  // staging: tile = 2048 chunks of 16B; chunk c: row=c>>3, slot=c&7,
  // global chunk g=(c&7)^(row&7); LDS dest linear c*16B.
  int rc[4], gc[4];
#pragma unroll
  for (int q = 0; q < 4; ++q) {
    int c = tid + q * 512;
    rc[q] = c >> 3;
    gc[q] = (c & 7) ^ (rc[q] & 7);
  }

  auto stage = [&](int t) {
    unsigned short* bufA = lds + (t & 1) * 32768;
    unsigned short* bufB = bufA + 16384;
    const unsigned short* As = Ae + t * 64;
    const unsigned short* Bs = Be + t * 64;
#pragma unroll
    for (int q = 0; q < 4; ++q) {
      gload_lds16(As + (size_t)rc[q] * Kt + gc[q] * 8, bufA + (tid + q * 512) * 8);
      gload_lds16(Bs + (size_t)rc[q] * Kt + gc[q] * 8, bufB + (tid + q * 512) * 8);
    }
  };

  // bias (vector loads, drained by first vmcnt(0))
  const float* be = bias + (size_t)e * Nt + nblk * 256;
  float bv[2];
#pragma unroll
  for (int ct = 0; ct < 2; ++ct) bv[ct] = be[wn * 64 + ct * 32 + l31];

  // fragment read offsets (shorts): frag(rowbase, kh): row = rowbase+l31,
  // chunk c = 2kh + l5, slot = c ^ (row&7), addr = row*64 + slot*8
  int offA[4][4], offB[2][4];
#pragma unroll
  for (int rt = 0; rt < 4; ++rt) {
    int row = wm * 128 + rt * 32 + l31;
#pragma unroll
    for (int kh = 0; kh < 4; ++kh)
      offA[rt][kh] = row * 64 + (((2 * kh + l5) ^ (row & 7)) << 3);
  }
#pragma unroll
  for (int ct = 0; ct < 2; ++ct) {
    int row = wn * 64 + ct * 32 + l31;
#pragma unroll
    for (int kh = 0; kh < 4; ++kh)
      offB[ct][kh] = row * 64 + (((2 * kh + l5) ^ (row & 7)) << 3);
  }

  f32x16 acc[4][2] = {};  // [rt][ct]

  stage(0);

  for (int t = 0; t < NT; ++t) {
    asm volatile("s_waitcnt vmcnt(0)" ::: "memory");  // tile t landed
    __builtin_amdgcn_s_barrier();                     // all waves agree
    if (t + 1 < NT) stage(t + 1);                     // other buffer

    const unsigned short* bufA = lds + (t & 1) * 32768;
    const unsigned short* bufB = bufA + 16384;

#pragma unroll
    for (int khp = 0; khp < 2; ++khp) {
      short8 fa[4][2], fb[2][2];
#pragma unroll
      for (int rt = 0; rt < 4; ++rt)
#pragma unroll
        for (int kq = 0; kq < 2; ++kq)
          fa[rt][kq] = *(const short8*)(bufA + offA[rt][khp * 2 + kq]);
#pragma unroll
      for (int ct = 0; ct < 2; ++ct)
#pragma unroll
        for (int kq = 0; kq < 2; ++kq)
          fb[ct][kq] = *(const short8*)(bufB + offB[ct][khp * 2 + kq]);

      __builtin_amdgcn_s_setprio(1);
#pragma unroll
      for (int kq = 0; kq < 2; ++kq)   // kh outermost: 8 indep MFMAs inside
#pragma unroll
        for (int rt = 0; rt < 4; ++rt)
#pragma unroll
          for (int ct = 0; ct < 2; ++ct)
            acc[rt][ct] = __builtin_amdgcn_mfma_f32_32x32x16_bf16(
                fa[rt][kq], fb[ct][kq], acc[rt][ct], 0, 0, 0);
      __builtin_amdgcn_s_setprio(0);
    }
  }
  __builtin_amdgcn_s_barrier();  // all reads retired (pre-MFMA lgkm waits)

  // C/D layout 32x32: col = l31, row = (reg&3) + 8*(reg>>2) + 4*l5
  if constexpr (EPI == 1) {
    // bounce to LDS [256][256] ushort with 16B-chunk XOR (ch ^= row&7)
#pragma unroll
    for (int rt = 0; rt < 4; ++rt)
#pragma unroll
      for (int ct = 0; ct < 2; ++ct)
#pragma unroll
        for (int reg = 0; reg < 16; ++reg) {
          int row = wm * 128 + rt * 32 + (reg & 3) + 8 * (reg >> 2) + 4 * l5;
          int col = wn * 64 + ct * 32 + l31;
          lds[row * 256 + (((col >> 3) ^ (row & 7)) << 3) + (col & 7)] =
              f2b(gelu_t(acc[rt][ct][reg] + bv[ct]));
        }
    __builtin_amdgcn_s_barrier();
    unsigned short* H = (unsigned short*)Cout;
#pragma unroll
    for (int j = 0; j < 16; ++j) {
      int row = j * 16 + wave * 2 + l5;
      int chk = l31;
      int sc = chk ^ (row & 7);
      unsigned short* dst =
          H + ((size_t)e * Mt + mblk * 256 + row) * Nt + nblk * 256 + chk * 8;
      *(int4*)dst = *(const int4*)(lds + row * 256 + sc * 8);
    }
  } else {
    // direct fp32 stores: per (rt,ct,reg) the 32 lanes of each half write a
    // contiguous 128B row segment
    float* O = (float*)Cout;
#pragma unroll
    for (int rt = 0; rt < 4; ++rt)
#pragma unroll
      for (int ct = 0; ct < 2; ++ct)
#pragma unroll
        for (int reg = 0; reg < 16; ++reg) {
          int row = wm * 128 + rt * 32 + (reg & 3) + 8 * (reg >> 2) + 4 * l5;
          int col = wn * 64 + ct * 32 + l31;
          O[((size_t)e * Mt + mblk * 256 + row) * Nt + nblk * 256 + col] =
              acc[rt][ct][reg] + bv[ct];
        }
  }
}

extern "C" void kernel_launch(void* const* d_in, const int* in_sizes, int n_in,
                              void* d_out, int out_size, void* d_ws, size_t ws_size,
                              hipStream_t stream) {
  const float* x = (const float*)d_in[0];
  const float* w1 = (const float*)d_in[1];
  const float* b1 = (const float*)d_in[2];
  const float* w2 = (const float*)d_in[3];
  const float* b2 = (const float*)d_in[4];
  float* out = (float*)d_out;

  unsigned short* ws = (unsigned short*)d_ws;
  unsigned short* xb = ws;                               // [T][D] bf16
  unsigned short* w1t = xb + (size_t)T_ * D_;            // [E][F][D] bf16
  unsigned short* w2t = w1t + (size_t)E_ * F_ * D_;      // [E][D][F] bf16
  unsigned short* h = w2t + (size_t)E_ * D_ * F_;        // [T][F] bf16

  cvt_bf16_kernel<<<2048, 256, 0, stream>>>(x, xb, T_ * D_);
  transpose_cvt<<<dim3((D_ / 32) * (F_ / 32), E_), 256, 0, stream>>>(w1, w1t, D_, F_);
  transpose_cvt<<<dim3((F_ / 32) * (D_ / 32), E_), 256, 0, stream>>>(w2, w2t, F_, D_);

  gemm32<C_, F_, D_, 1>
      <<<E_ * (C_ / 256) * (F_ / 256), 512, 0, stream>>>(xb, w1t, b1, h);
  gemm32<C_, D_, F_, 2>
      <<<E_ * (C_ / 256) * (D_ / 256), 512, 0, stream>>>(h, w2t, b2, out);
}